// Round 3
// baseline (735.192 us; speedup 1.0000x reference)
//
#include <hip/hip_runtime.h>

#define HIDDEN 51
#define LSEQ 1000
#define UNROLL 8    // steps buffered between butterfly/store groups

typedef float v2f __attribute__((ext_vector_type(2)));

// Branch-free tanh: tanh(v) = 1 - 2/(exp2(2*log2e*v)+1). Saturates to +/-1.
__device__ __forceinline__ float fast_tanh(float v) {
    float e = __builtin_amdgcn_exp2f(v * 2.885390081777927f);  // 2*log2(e)
    float r = __builtin_amdgcn_rcpf(e + 1.0f);
    return fmaf(-2.0f, r, 1.0f);
}

// R3: symmetric 2-wave k-split, ONE barrier per step.
// Evidence trail: R0 (1 wave/SIMD) 535us VALUBusy 44% = latency-bound, no
// HW hiding. R1 (2 batches/wave) VGPR 252, regressed. R2 (gate-split,
// 2 barriers + asymmetric tail bubble) 570us despite 2 waves/SIMD.
// Fix the R2 flaws, keep its occupancy win:
//  - k-split: wave0 sums all 4 gates over k=0..23, wave1 over k=24..50.
//    Each wave reads ONLY its h-slice (7 b128) -> LDS broadcast-return
//    bytes per CU unchanged vs R0 (gate-split would have 4x'd them).
//  - ONE __syncthreads/step: partials exchanged through a parity
//    double-buffered gb[par][wave][lane][4]; write(t)->read(t) ordered by
//    barrier(t); read(t)->overwrite(t+2) ordered by barrier(t+1). Proven
//    race-free by construction (2-deep buffer).
//  - Redundant symmetric tail: BOTH waves read both partial float4s in the
//    same order -> bitwise-identical c,h in each wave -> private per-wave
//    hb copy, zero cross-wave hb sync, no R2 idle bubble.
//  - Output duty split: wave0 butterflies+stores steps 0..3, wave1 4..7.
__global__ __launch_bounds__(128, 1) void lstm_seq_kernel(
    const float* __restrict__ x,
    const float* __restrict__ W_w,
    const float* __restrict__ W_b,
    const float* __restrict__ U_w,
    const float* __restrict__ U_b,
    const float* __restrict__ lin_w,
    const float* __restrict__ lin_b,
    float* __restrict__ out)
{
    __shared__ __attribute__((aligned(16))) float hb[2][64];        // per-wave h copy
    __shared__ __attribute__((aligned(16))) float gb[2][2][64][4];  // [par][wave][lane][gate]

    const int b    = blockIdx.x;
    const int tid  = threadIdx.x;
    const int wave = tid >> 6;           // 0 or 1 (wave-uniform)
    const int lane = tid & 63;           // 0..63
    const bool active = lane < HIDDEN;   // lanes 51..63 produce exact zeros
    const int m = active ? lane : 0;

    // k-slice: wave0 k=0..23 (j>=12 zero-padded), wave1 k=24..50 (51 padded).
    const int kbase = wave ? 24 : 0;
    const int kmax  = wave ? HIDDEN : 24;   // valid k upper bound (exclusive)

    float ww[4], bbias[4];
#pragma unroll
    for (int g = 0; g < 4; ++g) {
        const int row = m + g * HIDDEN;
        ww[g]    = active ? W_w[row] : 0.f;
        bbias[g] = active ? (W_b[row] + U_b[row]) : 0.f;
    }
    const float lw = active ? lin_w[m] : 0.f;
    const float lb = lin_b[0];

    // U packed over k-pairs within this wave's slice:
    // Up[g][j] = {U[row][kbase+2j], U[row][kbase+2j+1]}, zero outside slice.
    v2f Up[4][14];
#pragma unroll
    for (int j = 0; j < 14; ++j) {
        const int k0 = kbase + 2 * j, k1 = k0 + 1;
#pragma unroll
        for (int g = 0; g < 4; ++g) {
            const int row = m + g * HIDDEN;
            v2f u;
            u.x = (active && k0 < kmax) ? U_w[row * HIDDEN + k0] : 0.f;
            u.y = (active && k1 < kmax) ? U_w[row * HIDDEN + k1] : 0.f;
            Up[g][j] = u;
        }
    }

    float c = 0.f;
    const float* __restrict__ xrow = x + (long)b * LSEQ;
    float* __restrict__ orow = out + (long)b * LSEQ;

    hb[wave][lane] = 0.f;                 // own copy; own-wave ordering only
    __builtin_amdgcn_wave_barrier();
    const float* __restrict__ hslice = &hb[wave][kbase];  // 16B-aligned (96B ok)

    for (int T = 0; T < LSEQ; T += UNROLL) {
        float xg[UNROLL], rb[UNROLL];
#pragma unroll
        for (int s = 0; s < UNROLL; ++s) xg[s] = xrow[T + s];  // uniform

#pragma unroll
        for (int s = 0; s < UNROLL; ++s) {
            // 8 independent chains (4 gates x {lo,hi}), depth 7 each:
            // chain latency < issue (112cy), stays issue-bound.
            v2f aL[4], aH[4];
#pragma unroll
            for (int g = 0; g < 4; ++g) { aL[g] = (v2f){0.f, 0.f}; aH[g] = (v2f){0.f, 0.f}; }
#pragma unroll
            for (int q = 0; q < 7; ++q) {
                // Same-address b128 broadcast of own slice: conflict-free.
                const float4 hv = *(const float4*)&hslice[4 * q];
                const v2f hlo = {hv.x, hv.y};
                const v2f hhi = {hv.z, hv.w};
                aL[0] = __builtin_elementwise_fma(hlo, Up[0][2 * q],     aL[0]);
                aL[1] = __builtin_elementwise_fma(hlo, Up[1][2 * q],     aL[1]);
                aL[2] = __builtin_elementwise_fma(hlo, Up[2][2 * q],     aL[2]);
                aL[3] = __builtin_elementwise_fma(hlo, Up[3][2 * q],     aL[3]);
                aH[0] = __builtin_elementwise_fma(hhi, Up[0][2 * q + 1], aH[0]);
                aH[1] = __builtin_elementwise_fma(hhi, Up[1][2 * q + 1], aH[1]);
                aH[2] = __builtin_elementwise_fma(hhi, Up[2][2 * q + 1], aH[2]);
                aH[3] = __builtin_elementwise_fma(hhi, Up[3][2 * q + 1], aH[3]);
            }
            float4 d;
            d.x = (aL[0].x + aL[0].y) + (aH[0].x + aH[0].y);
            d.y = (aL[1].x + aL[1].y) + (aH[1].x + aH[1].y);
            d.z = (aL[2].x + aL[2].y) + (aH[2].x + aH[2].y);
            d.w = (aL[3].x + aL[3].y) + (aH[3].x + aH[3].y);

            // Exchange: contiguous b128 write (conflict-free), one barrier.
            *(float4*)&gb[s & 1][wave][lane][0] = d;
            __syncthreads();
            const float4 p0 = *(const float4*)&gb[s & 1][0][lane][0];
            const float4 p1 = *(const float4*)&gb[s & 1][1][lane][0];

            // Identical order in both waves -> bitwise-identical c,h.
            const float gi = (p0.x + p1.x) + fmaf(xg[s], ww[0], bbias[0]);
            const float gf = (p0.y + p1.y) + fmaf(xg[s], ww[1], bbias[1]);
            const float gg = (p0.z + p1.z) + fmaf(xg[s], ww[2], bbias[2]);
            const float go = (p0.w + p1.w) + fmaf(xg[s], ww[3], bbias[3]);

            // NOTE: faithful to reference -- no sigmoid on gates.
            c = fmaf(gf, c, gi * gg);
            const float h = go * fast_tanh(c);  // inactive lanes stay exactly 0

            __builtin_amdgcn_wave_barrier();    // own-slice reads precede write
            hb[wave][lane] = h;
            __builtin_amdgcn_wave_barrier();    // write precedes next reads
            rb[s] = h * lw;
        }

        // Output duty split: wave0 -> steps 0..3, wave1 -> steps 4..7.
        const int s0 = wave * 4;
#pragma unroll
        for (int si = 0; si < 4; ++si) {
#pragma unroll
            for (int off = 32; off > 0; off >>= 1)
                rb[s0 + si] += __shfl_xor(rb[s0 + si], off, 64);
        }
        if (lane == 0) {
            float4 o = {rb[s0] + lb, rb[s0 + 1] + lb, rb[s0 + 2] + lb, rb[s0 + 3] + lb};
            *(float4*)&orow[T + s0] = o;   // 16B-aligned (4000B row stride)
        }
    }
}

extern "C" void kernel_launch(void* const* d_in, const int* in_sizes, int n_in,
                              void* d_out, int out_size, void* d_ws, size_t ws_size,
                              hipStream_t stream) {
    const float* x     = (const float*)d_in[0];
    const float* W_w   = (const float*)d_in[1];
    const float* W_b   = (const float*)d_in[2];
    const float* U_w   = (const float*)d_in[3];
    const float* U_b   = (const float*)d_in[4];
    const float* lin_w = (const float*)d_in[5];
    const float* lin_b = (const float*)d_in[6];
    // d_in[7] = future (static 0; out_size == B*LSEQ)
    float* out = (float*)d_out;

    const int B = in_sizes[0] / LSEQ;  // 1024
    lstm_seq_kernel<<<dim3(B), dim3(128), 0, stream>>>(
        x, W_w, W_b, U_w, U_b, lin_w, lin_b, out);
}

// Round 4
// 488.263 us; speedup vs baseline: 1.5057x; 1.5057x over previous
//
#include <hip/hip_runtime.h>

#define HIDDEN 51
#define LSEQ 1000
#define UNROLL 8    // steps buffered between butterfly/store groups

typedef float v2f __attribute__((ext_vector_type(2)));

// Branch-free tanh: tanh(v) = 1 - 2/(exp2(2*log2e*v)+1). Saturates to +/-1.
__device__ __forceinline__ float fast_tanh(float v) {
    float e = __builtin_amdgcn_exp2f(v * 2.885390081777927f);  // 2*log2(e)
    float r = __builtin_amdgcn_rcpf(e + 1.0f);
    return fmaf(-2.0f, r, 1.0f);
}

// R4 = R0 structure + explicit full-depth LDS prefetch.
// Evidence trail: R1 (2 batch/wave, VGPR 252), R2 (gate-split, 2 barriers),
// R3 (k-split, 1 barrier) ALL regressed -> per-step cross-wave exchange
// costs more than its issue savings on a 1000-step serial recurrence.
// Single-wave R0 is the right structure.
// R0 stall audit: 1285 cy/step, 565 issue, ~700 stall; serial-path model
// accounts for only ~450 -> hypothesis: compiler keeps only ~2 of the 13
// hb broadcast ds_read_b128 in flight (VGPR_Count was just 128), exposing
// ~90cy of LDS latency per q. Fix: issue ALL 13 reads back-to-back into a
// register array (52 VGPRs -- free at 1 wave/SIMD, unified file is 512),
// then run the FMA block issue-bound. Plus: x*W+b folded into accumulator
// init (removes 4 serial adds from the tail).
__global__ __launch_bounds__(64, 1) void lstm_seq_kernel(
    const float* __restrict__ x,
    const float* __restrict__ W_w,
    const float* __restrict__ W_b,
    const float* __restrict__ U_w,
    const float* __restrict__ U_b,
    const float* __restrict__ lin_w,
    const float* __restrict__ lin_b,
    float* __restrict__ out)
{
    __shared__ __attribute__((aligned(16))) float hb[64];  // h broadcast

    const int b    = blockIdx.x;
    const int lane = threadIdx.x;        // 0..63
    const bool active = lane < HIDDEN;   // lanes 51..63 produce exact zeros
    const int m = active ? lane : 0;

    float ww[4], bbias[4];
#pragma unroll
    for (int g = 0; g < 4; ++g) {
        const int row = m + g * HIDDEN;
        ww[g]    = active ? W_w[row] : 0.f;
        bbias[g] = active ? (W_b[row] + U_b[row]) : 0.f;
    }
    const float lw = active ? lin_w[m] : 0.f;
    const float lb = lin_b[0];

    // U packed over k-pairs: Up[g][j] = {U[row][2j], U[row][2j+1]}, j<26.
    // k==51 is a zero pad (matches hb[51]==0 from lane 51's h==0).
    v2f Up[4][26];
#pragma unroll
    for (int j = 0; j < 26; ++j) {
        const int k0 = 2 * j, k1 = 2 * j + 1;
#pragma unroll
        for (int g = 0; g < 4; ++g) {
            const int row = m + g * HIDDEN;
            v2f u;
            u.x = (active && k0 < HIDDEN) ? U_w[row * HIDDEN + k0] : 0.f;
            u.y = (active && k1 < HIDDEN) ? U_w[row * HIDDEN + k1] : 0.f;
            Up[g][j] = u;
        }
    }

    float h = 0.f, c = 0.f;
    const float* __restrict__ xrow = x + (long)b * LSEQ;
    float* __restrict__ orow = out + (long)b * LSEQ;

    hb[lane] = 0.f;                       // single wave: in-order LDS pipe
    __builtin_amdgcn_wave_barrier();      // compile-time ordering insurance

    for (int T = 0; T < LSEQ; T += UNROLL) {
        float xg[UNROLL], rb[UNROLL];
#pragma unroll
        for (int s = 0; s < UNROLL; ++s) xg[s] = xrow[T + s];  // uniform

#pragma unroll
        for (int s = 0; s < UNROLL; ++s) {
            // Full-depth prefetch: all 13 same-address b128 broadcasts in
            // flight at once (conflict-free). 52 VGPRs of h, 13 lgkmcnt.
            float4 hv[13];
#pragma unroll
            for (int q = 0; q < 13; ++q) hv[q] = *(const float4*)&hb[q * 4];

            // Accumulators seeded with x*W + (W_b+U_b): tail = pure hsum.
            v2f a0 = {fmaf(xg[s], ww[0], bbias[0]), 0.f};
            v2f a1 = {fmaf(xg[s], ww[1], bbias[1]), 0.f};
            v2f a2 = {fmaf(xg[s], ww[2], bbias[2]), 0.f};
            v2f a3 = {fmaf(xg[s], ww[3], bbias[3]), 0.f};
#pragma unroll
            for (int q = 0; q < 13; ++q) {
                const v2f hlo = {hv[q].x, hv[q].y};
                const v2f hhi = {hv[q].z, hv[q].w};
                a0 = __builtin_elementwise_fma(hlo, Up[0][2 * q], a0);
                a1 = __builtin_elementwise_fma(hlo, Up[1][2 * q], a1);
                a2 = __builtin_elementwise_fma(hlo, Up[2][2 * q], a2);
                a3 = __builtin_elementwise_fma(hlo, Up[3][2 * q], a3);
                a0 = __builtin_elementwise_fma(hhi, Up[0][2 * q + 1], a0);
                a1 = __builtin_elementwise_fma(hhi, Up[1][2 * q + 1], a1);
                a2 = __builtin_elementwise_fma(hhi, Up[2][2 * q + 1], a2);
                a3 = __builtin_elementwise_fma(hhi, Up[3][2 * q + 1], a3);
            }
            const float gi = a0.x + a0.y;
            const float gf = a1.x + a1.y;
            const float gg = a2.x + a2.y;
            const float go = a3.x + a3.y;

            // NOTE: faithful to reference -- no sigmoid on gates.
            c = fmaf(gf, c, gi * gg);
            h = go * fast_tanh(c);        // inactive lanes stay exactly 0

            __builtin_amdgcn_wave_barrier();  // reads above precede write
            hb[lane] = h;
            __builtin_amdgcn_wave_barrier();  // write precedes next reads
            rb[s] = h * lw;
        }

        // 8 independent butterflies -- swizzle latencies overlap across s.
#pragma unroll
        for (int s = 0; s < UNROLL; ++s) {
#pragma unroll
            for (int off = 32; off > 0; off >>= 1)
                rb[s] += __shfl_xor(rb[s], off, 64);
        }
        if (lane == 0) {
            float4 o0 = {rb[0] + lb, rb[1] + lb, rb[2] + lb, rb[3] + lb};
            float4 o1 = {rb[4] + lb, rb[5] + lb, rb[6] + lb, rb[7] + lb};
            *(float4*)&orow[T]     = o0;   // orow 16B-aligned (b*4000 bytes)
            *(float4*)&orow[T + 4] = o1;
        }
    }
}

extern "C" void kernel_launch(void* const* d_in, const int* in_sizes, int n_in,
                              void* d_out, int out_size, void* d_ws, size_t ws_size,
                              hipStream_t stream) {
    const float* x     = (const float*)d_in[0];
    const float* W_w   = (const float*)d_in[1];
    const float* W_b   = (const float*)d_in[2];
    const float* U_w   = (const float*)d_in[3];
    const float* U_b   = (const float*)d_in[4];
    const float* lin_w = (const float*)d_in[5];
    const float* lin_b = (const float*)d_in[6];
    // d_in[7] = future (static 0; out_size == B*LSEQ)
    float* out = (float*)d_out;

    const int B = in_sizes[0] / LSEQ;  // 1024
    lstm_seq_kernel<<<dim3(B), dim3(64), 0, stream>>>(
        x, W_w, W_b, U_w, U_b, lin_w, lin_b, out);
}